// Round 7
// baseline (152.799 us; speedup 1.0000x reference)
//
#include <hip/hip_runtime.h>

#define BATCH 4
#define CHAN 128
#define HGT 96
#define WID 160
#define HW (HGT * WID)
#define THREADS 256
#define CG 4                 // channels per load/compute phase per wave

// Output channel index for displacement (dy,dx), matching _displacements(4) order.
__device__ __forceinline__ int chan_of(int dy, int dx) {
    if (dy == 0 && dx == 0) return 0;
    if (dx == 0) { int i = dy < 0 ? -dy : dy; return 1 + (i - 1) * 20 + (dy < 0 ? 0 : 1); }
    if (dy == 0) { int i = dx < 0 ? -dx : dx; return 1 + (i - 1) * 20 + (dx < 0 ? 2 : 3); }
    int i = dy < 0 ? -dy : dy;
    int j = dx < 0 ? -dx : dx;
    int s = (dy < 0) ? (dx < 0 ? 0 : 2) : (dx < 0 ? 3 : 1);
    return 1 + (i - 1) * 20 + 4 + (j - 1) * 4 + s;
}

// Static zero pad target for x-edge lanes: they point here with stride 0.
__device__ __align__(16) float g_zero4[4] = {0.f, 0.f, 0.f, 0.f};

// R6 post-mortem: latency-bound at ~9.6 waves/CU. This version: channel-split
// x4, 2160 blocks x 4 waves = 33.7 waves/CU; latency hidden by TLP. LDS only
// for the end-of-kernel combine tree (18.4 KB -> 8 blocks/CU possible).
__global__ __launch_bounds__(THREADS)
__attribute__((amdgpu_waves_per_eu(4, 8)))
void cost_volume_kernel(const float* __restrict__ src,
                        const float* __restrict__ tgt,
                        float* __restrict__ out) {
    __shared__ __align__(16) float4 s_comb[2][9][64];  // 18432 B combine buffer

    const int tid = threadIdx.x;
    const int q   = tid >> 6;         // channel quarter (wave-uniform)
    const int lid = tid & 63;         // px-lane within the 32x8 tile
    const int tx  = lid & 7;          // 4 px each along x -> 32 px wide
    const int ty  = lid >> 3;         // 0..7 rows
    const int px0 = tx * 4;

    // XCD-affinity swizzle (validated R6: FETCH 262->34 MB): blockIdx%8 picks
    // a (batch, y-half) slab; all blocks on one XCD stream the same ~8MB slab.
    const int w    = blockIdx.x;      // 0..2159
    const int slab = w & 7;
    const int b    = slab >> 1;
    const int yh   = slab & 1;
    const int r    = w >> 3;          // 0..269
    const int dy   = r % 9 - 4;
    const int t    = r / 9;           // 0..29
    const int x0   = (t % 5) * 32;
    const int y0   = (yh * 6 + t / 5) * 8;

    float4 acc[9];
    #pragma unroll
    for (int d = 0; d < 9; ++d) acc[d] = make_float4(0.f, 0.f, 0.f, 0.f);

    const int  row    = y0 + ty + dy;
    const bool row_ok = (unsigned)row < (unsigned)HGT;  // per-lane; exec-masked
    const int  xb     = x0 + px0;
    const bool okL    = (xb >= 4);
    const bool okR    = (xb <= 152);
    const int  c0     = q * (CHAN / 4);

    if (row_ok) {
        const float* ps    = src + ((b * CHAN + c0) * HGT + (y0 + ty)) * WID + xb;
        const float* tb    = tgt + ((b * CHAN + c0) * HGT + row) * WID;
        const float* pL    = okL ? (tb + xb - 4) : g_zero4;
        const float* pM    = tb + xb;
        const float* pR    = okR ? (tb + xb + 4) : g_zero4;
        const int    stepL = okL ? HW : 0;   // OOB lanes re-read the zero block
        const int    stepR = okR ? HW : 0;

        #pragma unroll 1
        for (int cg = 0; cg < (CHAN / 4) / CG; ++cg) {   // 8 phases of 4 channels
            // phase 1: 16 independent b128 loads in flight
            float4 sv[CG], w0[CG], w1[CG], w2[CG];
            #pragma unroll
            for (int c = 0; c < CG; ++c) {
                sv[c] = *reinterpret_cast<const float4*>(ps);
                w0[c] = *reinterpret_cast<const float4*>(pL);
                w1[c] = *reinterpret_cast<const float4*>(pM);
                w2[c] = *reinterpret_cast<const float4*>(pR);
                ps += HW; pL += stepL; pM += HW; pR += stepR;
            }
            // phase 2: 144 FMAs
            #pragma unroll
            for (int c = 0; c < CG; ++c) {
                float wv[12] = {w0[c].x, w0[c].y, w0[c].z, w0[c].w,
                                w1[c].x, w1[c].y, w1[c].z, w1[c].w,
                                w2[c].x, w2[c].y, w2[c].z, w2[c].w};
                float s[4]   = {sv[c].x, sv[c].y, sv[c].z, sv[c].w};
                #pragma unroll
                for (int d = 0; d < 9; ++d) {
                    acc[d].x += s[0] * wv[d];
                    acc[d].y += s[1] * wv[d + 1];
                    acc[d].z += s[2] * wv[d + 2];
                    acc[d].w += s[3] * wv[d + 3];
                }
            }
        }
    }

    // --- 2-stage combine tree across the 4 channel-quarter waves ---
    if (q >= 2) {                      // waves 2,3 publish
        #pragma unroll
        for (int d = 0; d < 9; ++d) s_comb[q - 2][d][lid] = acc[d];
    }
    __syncthreads();
    if (q < 2) {                       // waves 0,1 absorb
        #pragma unroll
        for (int d = 0; d < 9; ++d) {
            float4 p = s_comb[q][d][lid];
            acc[d].x += p.x; acc[d].y += p.y; acc[d].z += p.z; acc[d].w += p.w;
        }
    }
    __syncthreads();
    if (q == 1) {                      // wave 1 publishes its half-sum
        #pragma unroll
        for (int d = 0; d < 9; ++d) s_comb[0][d][lid] = acc[d];
    }
    __syncthreads();
    if (q == 0) {                      // wave 0 finalizes + stores
        const float inv = 1.0f / 81.0f;
        const int gy = y0 + ty;
        #pragma unroll
        for (int d = 0; d < 9; ++d) {
            float4 p = s_comb[0][d][lid];
            int oc = chan_of(dy, d - 4);
            float4 o = make_float4((acc[d].x + p.x) * inv, (acc[d].y + p.y) * inv,
                                   (acc[d].z + p.z) * inv, (acc[d].w + p.w) * inv);
            *reinterpret_cast<float4*>(
                out + ((b * 81 + oc) * HGT + gy) * WID + xb) = o;
        }
    }
}

extern "C" void kernel_launch(void* const* d_in, const int* in_sizes, int n_in,
                              void* d_out, int out_size, void* d_ws, size_t ws_size,
                              hipStream_t stream) {
    const float* src = (const float*)d_in[0];
    const float* tgt = (const float*)d_in[1];
    float* out = (float*)d_out;
    cost_volume_kernel<<<dim3(2160, 1, 1), dim3(THREADS, 1, 1), 0, stream>>>(src, tgt, out);
}

// Round 8
// 150.350 us; speedup vs baseline: 1.0163x; 1.0163x over previous
//
#include <hip/hip_runtime.h>

#define BATCH 4
#define CHAN 128
#define HGT 96
#define WID 160
#define HW (HGT * WID)
#define THREADS 256

typedef __attribute__((ext_vector_type(8))) short short8;
typedef __attribute__((ext_vector_type(4))) float float4v;

// Output channel index for displacement (dy,dx), matching _displacements(4) order.
__device__ __forceinline__ int chan_of(int dy, int dx) {
    if (dy == 0 && dx == 0) return 0;
    if (dx == 0) { int i = dy < 0 ? -dy : dy; return 1 + (i - 1) * 20 + (dy < 0 ? 0 : 1); }
    if (dy == 0) { int i = dx < 0 ? -dx : dx; return 1 + (i - 1) * 20 + (dx < 0 ? 2 : 3); }
    int i = dy < 0 ? -dy : dy;
    int j = dx < 0 ? -dx : dx;
    int s = (dy < 0) ? (dx < 0 ? 0 : 2) : (dx < 0 ? 3 : 1);
    return 1 + (i - 1) * 20 + 4 + (j - 1) * 4 + s;
}

// fp32 -> bf16 round-to-nearest-even (inputs are finite normals; no NaN path).
__device__ __forceinline__ short bf16rne(float x) {
    unsigned u = __float_as_uint(x);
    unsigned r = (u + 0x7fffu + ((u >> 16) & 1u)) >> 16;
    return (short)r;
}

// MFMA cost-volume: per (b, y, dy) a banded GEMM C[x,x'] = sum_c src*tgt.
// M=16 px (A: lane&15), N=2x16 px' window, K=128 via 4x mfma 16x16x32 bf16.
// No LDS, no barriers: fragments gathered straight from global; TLP hides
// latency. waves_per_eu(4,5): cap 102 VGPR — enough for 24 acc + 16 afr +
// transients without spill (R2 lesson) and without restage-starving (R7).
__global__ __launch_bounds__(THREADS)
__attribute__((amdgpu_waves_per_eu(4, 5)))
void cost_volume_kernel(const float* __restrict__ src,
                        const float* __restrict__ tgt,
                        float* __restrict__ out) {
    const int tid  = threadIdx.x;
    const int wid  = tid >> 6;        // wave in block -> y offset
    const int lane = tid & 63;
    const int q    = lane >> 4;       // quad
    const int ln   = lane & 15;       // m (A) / n (B) index

    // XCD-affinity swizzle (validated R6): blockIdx%8 -> (batch, y-half) slab.
    const int w    = blockIdx.x;      // 0..2879
    const int slab = w & 7;
    const int b    = slab >> 1;
    const int yh   = slab & 1;
    const int r    = w >> 3;          // 0..359
    const int dyg  = r % 3;
    const int t    = r / 3;           // 0..119
    const int x0   = (t % 10) * 16;
    const int y0   = yh * 48 + (t / 10) * 4;
    const int dy0  = dyg * 3 - 4;     // this block's dys: dy0..dy0+2
    const int y    = y0 + wid;

    const int koff = q * 8 * HW;      // per-lane k base offset (quad*8 channels)

    // ---- A fragments: A[m=ln][k=q*8+j], src[b, k, y, x0+ln]; reused 6x ----
    const float* sb = src + (b * CHAN * HGT + y) * WID + x0 + ln;
    short8 afr[4];
    #pragma unroll
    for (int ks = 0; ks < 4; ++ks) {
        float av[8];
        #pragma unroll
        for (int j = 0; j < 8; ++j)
            av[j] = sb[koff + (ks * 32 + j) * HW];
        short8 f;
        #pragma unroll
        for (int j = 0; j < 8; ++j) f[j] = bf16rne(av[j]);
        afr[ks] = f;
    }

    float4v acc[3][2];
    #pragma unroll
    for (int g = 0; g < 3; ++g)
        #pragma unroll
        for (int nt = 0; nt < 2; ++nt)
            acc[g][nt] = (float4v){0.f, 0.f, 0.f, 0.f};

    // lane x' per N-tile (clamped; OOB lanes zero their fragment)
    const int  xq0  = x0 - 4 + ln;
    const int  xq1  = x0 + 12 + ln;
    const bool xok0 = (unsigned)xq0 < (unsigned)WID;
    const bool xok1 = (unsigned)xq1 < (unsigned)WID;
    const int  xc0  = xok0 ? xq0 : 0;
    const int  xc1  = xok1 ? xq1 : 0;

    #pragma unroll
    for (int g = 0; g < 3; ++g) {
        const int row = y + dy0 + g;             // wave-uniform
        if ((unsigned)row < (unsigned)HGT) {
            const float* tb0 = tgt + (b * CHAN * HGT + row) * WID + xc0;
            const float* tb1 = tgt + (b * CHAN * HGT + row) * WID + xc1;
            #pragma unroll
            for (int ks = 0; ks < 4; ++ks) {
                // 16 independent dword gathers in flight, then 2 MFMAs
                float b0[8], b1[8];
                #pragma unroll
                for (int j = 0; j < 8; ++j)
                    b0[j] = tb0[koff + (ks * 32 + j) * HW];
                #pragma unroll
                for (int j = 0; j < 8; ++j)
                    b1[j] = tb1[koff + (ks * 32 + j) * HW];
                short8 f0, f1;
                #pragma unroll
                for (int j = 0; j < 8; ++j) {
                    f0[j] = bf16rne(xok0 ? b0[j] : 0.f);
                    f1[j] = bf16rne(xok1 ? b1[j] : 0.f);
                }
                acc[g][0] = __builtin_amdgcn_mfma_f32_16x16x32_bf16(
                    afr[ks], f0, acc[g][0], 0, 0, 0);
                acc[g][1] = __builtin_amdgcn_mfma_f32_16x16x32_bf16(
                    afr[ks], f1, acc[g][1], 0, 0, 0);
            }
        }
        // row OOB: acc stays 0 -> epilogue writes the required zeros
    }

    // ---- epilogue: band extraction from C/D layout (col=ln, row=q*4+reg) ----
    const float inv = 1.0f / 81.0f;
    #pragma unroll
    for (int g = 0; g < 3; ++g) {
        const int dy = dy0 + g;
        #pragma unroll
        for (int nt = 0; nt < 2; ++nt) {
            #pragma unroll
            for (int reg = 0; reg < 4; ++reg) {
                int m  = q * 4 + reg;            // output x = x0 + m
                int dx = nt * 16 + ln - 4 - m;   // x' - x
                if (dx >= -4 && dx <= 4) {       // exec-masked scatter store
                    int oc = chan_of(dy, dx);
                    out[((b * 81 + oc) * HGT + y) * WID + x0 + m] =
                        acc[g][nt][reg] * inv;
                }
            }
        }
    }
}

extern "C" void kernel_launch(void* const* d_in, const int* in_sizes, int n_in,
                              void* d_out, int out_size, void* d_ws, size_t ws_size,
                              hipStream_t stream) {
    const float* src = (const float*)d_in[0];
    const float* tgt = (const float*)d_in[1];
    float* out = (float*)d_out;
    cost_volume_kernel<<<dim3(2880, 1, 1), dim3(THREADS, 1, 1), 0, stream>>>(src, tgt, out);
}